// Round 2
// baseline (154.034 us; speedup 1.0000x reference)
//
#include <hip/hip_runtime.h>
#include <float.h>

// ReconGraph: connected[y][x] = OR over 4 diagonal neighbors of
// (|d[y+dy][x+dx] - d[y][x]| <= threshold); output = connected.T as int32 0/1.
// Memory-bound stencil + transpose. 64x64 tiles via LDS, int4 stores.

constexpr int TILE = 64;
constexpr int LDSW = 67;  // odd pad -> conflict-free LDS reads

__global__ __launch_bounds__(256, 4)
void recon_kernel(const float* __restrict__ d, const float* __restrict__ thrp,
                  int* __restrict__ out, int M, int N) {
    __shared__ float t[TILE + 2][LDSW];
    const float thr = thrp[0];
    const int x0 = blockIdx.x * TILE;
    const int y0 = blockIdx.y * TILE;
    const int tid = threadIdx.x;

    // Load (TILE+2) x (TILE+2) halo tile. t[r][c] = d[y0-1+r][x0-1+c], OOB -> FLT_MAX.
    for (int idx = tid; idx < (TILE + 2) * (TILE + 2); idx += 256) {
        int r = idx / (TILE + 2);
        int c = idx - r * (TILE + 2);
        int gy = y0 - 1 + r;
        int gx = x0 - 1 + c;
        float v = FLT_MAX;
        if ((unsigned)gy < (unsigned)M && (unsigned)gx < (unsigned)N)
            v = d[(size_t)gy * (size_t)N + (size_t)gx];
        t[r][c] = v;
    }
    __syncthreads();

    // Transposed-order compute: each wave handles fixed x per 16-lane group,
    // lanes sweep y in quads -> int4 coalesced stores to out[x*M + y].
    const int lane = tid & 63;
    const int wave = tid >> 6;
    const int yq = (lane & 15) * 4;   // y offset within tile (quad base)
    const int xg = lane >> 4;         // x subgroup 0..3

#pragma unroll
    for (int k = 0; k < 4; ++k) {
        const int x = xg + 4 * wave + 16 * k;   // 0..63 over waves/k
        // neighbors: cols x (dx=-1) and x+2 (dx=+1), rows yq..yq+5;
        // centers: col x+1, rows yq+1..yq+4
        float lft[6], rgt[6], ctr[4];
#pragma unroll
        for (int i = 0; i < 6; ++i) {
            lft[i] = t[yq + i][x];
            rgt[i] = t[yq + i][x + 2];
        }
#pragma unroll
        for (int i = 0; i < 4; ++i) ctr[i] = t[yq + 1 + i][x + 1];

        int4 o;
        int* op = &o.x;
#pragma unroll
        for (int i = 0; i < 4; ++i) {
            const float c = ctr[i];
            bool conn = (fabsf(lft[i] - c) <= thr) |
                        (fabsf(rgt[i] - c) <= thr) |
                        (fabsf(lft[i + 2] - c) <= thr) |
                        (fabsf(rgt[i + 2] - c) <= thr);
            op[i] = conn ? 1 : 0;
        }
        *reinterpret_cast<int4*>(out + (size_t)(x0 + x) * (size_t)M + (size_t)(y0 + yq)) = o;
    }
}

extern "C" void kernel_launch(void* const* d_in, const int* in_sizes, int n_in,
                              void* d_out, int out_size, void* d_ws, size_t ws_size,
                              hipStream_t stream) {
    const float* d   = (const float*)d_in[0];
    const float* thr = (const float*)d_in[1];
    int* out = (int*)d_out;
    const int M = 8192, N = 8192;   // out_size == M*N
    dim3 grid(N / TILE, M / TILE);
    recon_kernel<<<grid, dim3(256), 0, stream>>>(d, thr, out, M, N);
}

// Round 6
// 153.869 us; speedup vs baseline: 1.0011x; 1.0011x over previous
//
#include <hip/hip_runtime.h>
#include <float.h>

// ReconGraph: out[x][y] = OR over 4 diagonal neighbors of (|d[y+dy][x+dx] - d[y][x]| <= thr),
// OOB neighbor = FLT_MAX (never connects). Output int32 0/1, transposed.
//
// No-LDS design: each thread computes a 4x4 output micro-tile (x = gx..gx+3, y = gy..gy+3)
// straight from registers. 18 float4 loads (6 rows x 3 overlapping quads; overlap hits L1),
// 4 int4 stores. No barriers, no LDS. Interior blocks take a guard-free path.

#define BIG4 make_float4(FLT_MAX, FLT_MAX, FLT_MAX, FLT_MAX)

template<bool EDGE>
__device__ __forceinline__ void recon_body(const float* __restrict__ d, float thr,
                                           int* __restrict__ out, int bx, int by, int tid) {
    const int xq = tid & 15;        // fast index -> coalesced 256B load groups
    const int yq = tid >> 4;
    const int gx = bx * 64 + 4 * xq;
    const int gy = by * 64 + 4 * yq;

    // s[j][t] = d[gy-1+j][gx-1+t], j=0..5, t=0..5 (span cols gx-1 .. gx+4)
    float s[6][6];
#pragma unroll
    for (int j = 0; j < 6; ++j) {
        const int yy = gy - 1 + j;
        float4 a, b, c;
        if (!EDGE) {
            const float4* p = (const float4*)(d + ((size_t)yy << 13) + gx);
            a = p[-1];          // cols gx-4 .. gx-1 (need .w)
            b = p[0];           // cols gx   .. gx+3
            c = p[1];           // cols gx+4 .. gx+7 (need .x)
        } else {
            const bool yok = (unsigned)yy < 8192u;
            const float4* p = (const float4*)(d + ((size_t)(yok ? yy : 0) << 13) + gx);
            a = (yok && gx >= 4)        ? p[-1] : BIG4;
            b = yok                      ? p[0]  : BIG4;
            c = (yok && gx + 7 < 8192)   ? p[1]  : BIG4;
        }
        s[j][0] = a.w; s[j][1] = b.x; s[j][2] = b.y;
        s[j][3] = b.z; s[j][4] = b.w; s[j][5] = c.x;
    }

#pragma unroll
    for (int i = 0; i < 4; ++i) {       // output row x = gx+i
        int r[4];
#pragma unroll
        for (int k = 0; k < 4; ++k) {   // output col y = gy+k
            const float ctr = s[k + 1][i + 1];
            bool conn = (fabsf(s[k][i]     - ctr) <= thr) |
                        (fabsf(s[k][i + 2] - ctr) <= thr) |
                        (fabsf(s[k + 2][i]     - ctr) <= thr) |
                        (fabsf(s[k + 2][i + 2] - ctr) <= thr);
            r[k] = conn ? 1 : 0;
        }
        *reinterpret_cast<int4*>(out + ((size_t)(gx + i) << 13) + gy) =
            make_int4(r[0], r[1], r[2], r[3]);
    }
}

__global__ __launch_bounds__(256, 4)
void recon_kernel(const float* __restrict__ d, const float* __restrict__ thrp,
                  int* __restrict__ out) {
    const float thr = thrp[0];
    const int bx = blockIdx.x, by = blockIdx.y;
    if (bx >= 1 && bx <= 126 && by >= 1 && by <= 126) {
        recon_body<false>(d, thr, out, bx, by, threadIdx.x);
    } else {
        recon_body<true>(d, thr, out, bx, by, threadIdx.x);
    }
}

extern "C" void kernel_launch(void* const* d_in, const int* in_sizes, int n_in,
                              void* d_out, int out_size, void* d_ws, size_t ws_size,
                              hipStream_t stream) {
    const float* d   = (const float*)d_in[0];
    const float* thr = (const float*)d_in[1];
    int* out = (int*)d_out;
    dim3 grid(128, 128);
    recon_kernel<<<grid, dim3(256), 0, stream>>>(d, thr, out);
}